// Round 6
// baseline (144.904 us; speedup 1.0000x reference)
//
#include <hip/hip_runtime.h>
#include <math.h>

// SSIM loss, fp32 in, B=16 C=3 H=W=512, 11x11 Gaussian (sigma=1.5), zero pad.
// R15: pure-TLP restructure. Waves fully independent, zero barriers.
//  - 2-wave blocks (NT=128); each wave owns 16 out cols x 128 out rows, its
//    own 5.1 KB Ht region, its own partials slot. No __syncthreads at all.
//  - LDS 10.25 KB/block -> 15 blocks/CU LDS-limit; launch_bounds(128,7)
//    caps VGPR ~73 -> target ~28-30 waves/CU (2.4x the measured 12).
//    R11-R14 post-mortems: VALUBusy*dur ~= 17 us ~= HBM floor 16.3 us; the
//    3x gap to 47 us is latency that 12 waves/CU cannot hide. TLP is the
//    remaining lever; per-wave ILP attempts were undone by the compiler
//    (VGPR pinned at 44-48, loads sunk) and sched_barrier pins regressed.
//  - 2-slot Ht ring (vconv m reads chunks m,m+1 via per-lane slot select;
//    hconv overwrites slot (m)&1 AFTER the reads -- same-wave DS ordering).
// Math identical to R10-R14 (S=x+y, D=x-y planes, f16 pipeline, cv fixup).
// gfx950 v_mfma_f32_16x16x32_f16 layouts (verified R10-R14 pass):
//   A[i][k]: lane = i + 16*(k/8), elem = k%8
//   B[k][j]: lane = j + 16*(k/8), elem = k%8
//   D[r][c]: lane = c + 16*(r/4), reg  = r%4

#define IMG_W 512
#define IMG_H 512
#define PLANES 48
#define TYS 128
#define RAD 5
#define NT 128
#define NWAVES (PLANES * 32 * (IMG_H / TYS))   // 6144
#define NBLKS (NWAVES / 2)                     // 3072
#define NCH 9                       // hconv 16-row chunks (144 H rows)
#define NCV 8                       // vconv out chunks (128 out rows)
#define CSTR 40                     // Ht col stride, f16 (2 slots*16 + 8 pad)
#define PSTR (16 * CSTR)            // Ht plane stride, f16 (640)
#define WSTR (4 * PSTR)             // Ht wave stride, f16 (2560)
#define NUMREC (IMG_W * IMG_H * 4)  // SRD num_records (bytes)
#define CHSTEP (16 * IMG_W * 4)     // voffset step per 16-row chunk (32768)
#define INVW  0.26601181f           // 1 / sum(exp(-(k-5)^2/4.5))
#define GC2   0.32059890f           // (1/4.5) * log2(e)

typedef _Float16 h2 __attribute__((ext_vector_type(2)));
typedef _Float16 h4 __attribute__((ext_vector_type(4)));
typedef _Float16 h8 __attribute__((ext_vector_type(8)));
typedef float f32x4 __attribute__((ext_vector_type(4)));
typedef int i32x4 __attribute__((ext_vector_type(4)));

// CK-style direct binding to the raw buffer-load intrinsic: hardware
// bounds-check vs num_records; OOB lanes read 0. Compiler tracks vmcnt.
__device__ f32x4 buf_ld_x4(i32x4 srsrc, int voffset, int soffset, int aux)
    __asm("llvm.amdgcn.raw.buffer.load.v4f32");

__device__ __forceinline__ i32x4 make_srd(const float* p) {
    union { i32x4 v; struct { const float* p; unsigned rng; unsigned cfg; } s; } u;
    u.s.p = p; u.s.rng = NUMREC; u.s.cfg = 0x00020000u;
    return u.v;
}

__device__ __forceinline__ float exp2_fast(float a) {
#if __has_builtin(__builtin_amdgcn_exp2f)
    return __builtin_amdgcn_exp2f(a);
#else
    return exp2f(a);
#endif
}

// Normalized f32 Gaussian weight w[idx], idx in [0,10], else 0.
__device__ __forceinline__ float wbandf(int idx) {
    const float fd = (float)(idx - 5);
    const float g = exp2_fast(-(fd * fd) * GC2) * INVW;
    return ((unsigned)idx <= 10u) ? g : 0.f;
}

__device__ __forceinline__ h2 pkrtz(float a, float b) {
    auto t = __builtin_amdgcn_cvt_pkrtz(a, b);
    h2 r;
    __builtin_memcpy(&r, &t, sizeof(r));
    return r;
}

__device__ __forceinline__ h4 pack4(f32x4 a) {
    const h2 lo = pkrtz(a[0], a[1]), hi = pkrtz(a[2], a[3]);
    h4 v;
    v[0] = lo.x; v[1] = lo.y; v[2] = hi.x; v[3] = hi.y;
    return v;
}

// One 16-row hconv chunk: regs -> s/d/s2/d2 MFMA -> transposed f16 Ht slot.
__device__ __forceinline__ void hconv_chunk(
    f32x4 xa, f32x4 xb, f32x4 ya, f32x4 yb, h8 whB,
    _Float16* wp)    // = Hw + fc*CSTR + 4*q + slot*16
{
    const f32x4 zz = {0.f, 0.f, 0.f, 0.f};
    const h2 xh0 = pkrtz(xa[0], xa[1]), xh1 = pkrtz(xa[2], xa[3]);
    const h2 xh2 = pkrtz(xb[0], xb[1]), xh3 = pkrtz(xb[2], xb[3]);
    const h2 yh0 = pkrtz(ya[0], ya[1]), yh1 = pkrtz(ya[2], ya[3]);
    const h2 yh2 = pkrtz(yb[0], yb[1]), yh3 = pkrtz(yb[2], yb[3]);
    const h2 s0 = xh0 + yh0, s1 = xh1 + yh1, s2 = xh2 + yh2, s3 = xh3 + yh3;
    const h2 d0 = xh0 - yh0, d1 = xh1 - yh1, d2 = xh2 - yh2, d3 = xh3 - yh3;
    h8 sA, dA;
    sA[0] = s0.x; sA[1] = s0.y; sA[2] = s1.x; sA[3] = s1.y;
    sA[4] = s2.x; sA[5] = s2.y; sA[6] = s3.x; sA[7] = s3.y;
    dA[0] = d0.x; dA[1] = d0.y; dA[2] = d1.x; dA[3] = d1.y;
    dA[4] = d2.x; dA[5] = d2.y; dA[6] = d3.x; dA[7] = d3.y;
    const h8 s2A = sA * sA;                       // v_pk_mul_f16
    const h8 d2A = dA * dA;
    const f32x4 hS  = __builtin_amdgcn_mfma_f32_16x16x32_f16(sA,  whB, zz, 0, 0, 0);
    const f32x4 hD  = __builtin_amdgcn_mfma_f32_16x16x32_f16(dA,  whB, zz, 0, 0, 0);
    const f32x4 hS2 = __builtin_amdgcn_mfma_f32_16x16x32_f16(s2A, whB, zz, 0, 0, 0);
    const f32x4 hD2 = __builtin_amdgcn_mfma_f32_16x16x32_f16(d2A, whB, zz, 0, 0, 0);
    *(h4*)(wp + 0 * PSTR) = pack4(hS);            // ds_write_b64
    *(h4*)(wp + 1 * PSTR) = pack4(hD);
    *(h4*)(wp + 2 * PSTR) = pack4(hS2);
    *(h4*)(wp + 3 * PSTR) = pack4(hD2);
}

// SSIM map for one completed out-chunk (4 rows of one col per lane).
__device__ __forceinline__ float mapsum(f32x4 aS, f32x4 aD, f32x4 aS2, f32x4 aD2,
                                        float cv)
{
    float local = 0.f;
    #pragma unroll
    for (int r = 0; r < 4; ++r) {
        const float mS = aS[r]  * cv, mD = aD[r]  * cv;
        const float eS = aS2[r] * cv, eD = aD2[r] * cv;
        const float ms2 = mS * mS, md2 = mD * mD;
        const float Pm = 0.5f * (ms2 - md2);   // = 2*mu_x*mu_y
        const float Qm = 0.5f * (ms2 + md2);   // = mu_x^2 + mu_y^2
        const float Pe = 0.5f * (eS - eD);     // = 2*E[xy]
        const float Qe = 0.5f * (eS + eD);     // = E[x^2 + y^2]
        const float c1 = 1e-4f, c2 = 9e-4f;
        const float num = (Pm + c1) * (Pe - Pm + c2);
        const float den = (Qm + c1) * (Qe - Qm + c2) + 1e-8f;
        local += num * __builtin_amdgcn_rcpf(den);
    }
    return local;
}

#define MFMA16(A, B, C) __builtin_amdgcn_mfma_f32_16x16x32_f16((A), (B), (C), 0, 0, 0)

__global__ __launch_bounds__(NT, 7) void ssim_tile_kernel(
    const float* __restrict__ x, const float* __restrict__ y,
    float* __restrict__ partials)
{
    __shared__ __align__(16) _Float16 Ht[2 * WSTR];   // 10240 B

    const int tid = threadIdx.x;
    const int l = tid & 63, wid = tid >> 6;
    const int q = l >> 4, fc = l & 15;
    const int ql = q & 1, qh = q >> 1;

    // wave -> (plane, row strip, 16-col group)
    const int gid = blockIdx.x * 2 + wid;
    const int plane = gid >> 7;
    const int rem = gid & 127;
    const int R0 = (rem >> 5) * TYS;
    const int C0 = (rem & 31) * 16;

    const i32x4 srdx = make_srd(x + (size_t)plane * IMG_H * IMG_W);
    const i32x4 srdy = make_srd(y + (size_t)plane * IMG_H * IMG_W);
    const int gcol = C0 - 8 + 8 * q;            // A-frag global col start
    // Row OOB -> voffset outside [0,NUMREC) -> HW returns 0.
    // Col OOB lanes (gcol=-8 or 512): permanently-OOB voffset.
    int voff = ((unsigned)gcol < (unsigned)IMG_W)
             ? (((R0 - RAD + fc) << 11) + (gcol << 2)) : 0x60000000;

    // ---- Prologue: issue chunks 0,1 into reg ring slots 0,1 ----
    f32x4 LXA[2], LXB[2], LYA[2], LYB[2];
    #pragma unroll
    for (int cpl = 0; cpl < 2; ++cpl) {
        LXA[cpl] = buf_ld_x4(srdx, voff, 0, 0);
        LXB[cpl] = buf_ld_x4(srdx, voff, 16, 0);
        LYA[cpl] = buf_ld_x4(srdy, voff, 0, 0);
        LYB[cpl] = buf_ld_x4(srdy, voff, 16, 0);
        voff += CHSTEP;
    }

    // ---- Weight setup (executes under the in-flight loads) ----
    float s2w = 0.f;
    #pragma unroll
    for (int k = 0; k <= 10; ++k) s2w += (float)(_Float16)wbandf(k);
    const float cv = 1.f / (s2w * s2w);

    h8 whB, wvA;                 // hconv B-frag w[t-u-3], vconv A-frag w[t-u]
    #pragma unroll
    for (int e = 0; e < 8; ++e) {
        whB[e] = (_Float16)wbandf(8 * q + e - fc - 3);
        wvA[e] = (_Float16)wbandf(8 * q + e - fc);
    }

    _Float16* const Hw = Ht + wid * WSTR;                    // this wave's region
    _Float16* const hwr = Hw + fc * CSTR + 4 * q;            // write base (+slot*16)
    const _Float16* const rbase = Hw + fc * CSTR + 8 * ql;   // read base (+slot*16)

    const f32x4 zz = {0.f, 0.f, 0.f, 0.f};
    float local = 0.f;

    // ---- Main loop: vconv out m=c-2 | hconv chunk c | refill ring ----
    #pragma unroll
    for (int c = 0; c < NCH; ++c) {
        if (c >= 2) {
            // out chunk m=c-2 reads H chunks m (slot c&1, qh=0 lanes) and
            // m+1 (slot (c+1)&1, qh=1 lanes): per-lane slot = (c+qh)&1
            const _Float16* rp = rbase + (((c + qh) & 1) << 4);
            const h8 B0 = *(const h8*)(rp + 0 * PSTR);       // ds_read_b128 x4
            const h8 B1 = *(const h8*)(rp + 1 * PSTR);
            const h8 B2 = *(const h8*)(rp + 2 * PSTR);
            const h8 B3 = *(const h8*)(rp + 3 * PSTR);
            const f32x4 aS  = MFMA16(wvA, B0, zz);
            const f32x4 aD  = MFMA16(wvA, B1, zz);
            const f32x4 aS2 = MFMA16(wvA, B2, zz);
            const f32x4 aD2 = MFMA16(wvA, B3, zz);
            local += mapsum(aS, aD, aS2, aD2, cv);
        }
        // hconv chunk c -> slot c&1 (overwrites chunk c-2 AFTER the reads
        // above; same-wave DS ops execute in order -> no barrier needed)
        hconv_chunk(LXA[c & 1], LXB[c & 1], LYA[c & 1], LYB[c & 1],
                    whB, hwr + ((c & 1) << 4));
        if (c + 2 < NCH) {                       // refill ring with chunk c+2
            LXA[c & 1] = buf_ld_x4(srdx, voff, 0, 0);
            LXB[c & 1] = buf_ld_x4(srdx, voff, 16, 0);
            LYA[c & 1] = buf_ld_x4(srdy, voff, 0, 0);
            LYB[c & 1] = buf_ld_x4(srdy, voff, 16, 0);
            voff += CHSTEP;
        }
    }

    // ---- Epilogue: out chunk m=NCV-1=7 (reads chunks 7,8) ----
    {
        const _Float16* rp = rbase + ((((NCH - 2) + qh) & 1) << 4);
        const h8 B0 = *(const h8*)(rp + 0 * PSTR);
        const h8 B1 = *(const h8*)(rp + 1 * PSTR);
        const h8 B2 = *(const h8*)(rp + 2 * PSTR);
        const h8 B3 = *(const h8*)(rp + 3 * PSTR);
        const f32x4 aS  = MFMA16(wvA, B0, zz);
        const f32x4 aD  = MFMA16(wvA, B1, zz);
        const f32x4 aS2 = MFMA16(wvA, B2, zz);
        const f32x4 aD2 = MFMA16(wvA, B3, zz);
        local += mapsum(aS, aD, aS2, aD2, cv);
    }

    // ---- Wave reduction -> one partial per wave (no barrier) ----
    #pragma unroll
    for (int off = 32; off > 0; off >>= 1)
        local += __shfl_down(local, off, 64);
    if (l == 0) partials[gid] = local;
}

__global__ __launch_bounds__(256) void ssim_finalize_kernel(
    const float* __restrict__ partials, float* __restrict__ out)
{
    const int tid = threadIdx.x;
    double s = 0.0;
    #pragma unroll 4
    for (int i = tid; i < NWAVES; i += 256) s += (double)partials[i];
    #pragma unroll
    for (int off = 32; off > 0; off >>= 1)
        s += __shfl_down(s, off, 64);
    __shared__ double ws_[256 / 64];
    const int lane = tid & 63, wv = tid >> 6;
    if (lane == 0) ws_[wv] = s;
    __syncthreads();
    if (tid == 0) {
        const double t = ws_[0] + ws_[1] + ws_[2] + ws_[3];
        const double n = (double)PLANES * IMG_H * IMG_W;
        out[0] = (float)(1.0 - t / n);
    }
}

extern "C" void kernel_launch(void* const* d_in, const int* in_sizes, int n_in,
                              void* d_out, int out_size, void* d_ws, size_t ws_size,
                              hipStream_t stream)
{
    const float* x = (const float*)d_in[0];
    const float* y = (const float*)d_in[1];
    float* out = (float*)d_out;
    float* partials = (float*)d_ws;   // NWAVES floats, fully overwritten each call

    dim3 grid(NBLKS, 1, 1);
    ssim_tile_kernel<<<grid, NT, 0, stream>>>(x, y, partials);
    ssim_finalize_kernel<<<1, 256, 0, stream>>>(partials, out);
}

// Round 7
// 131.200 us; speedup vs baseline: 1.1044x; 1.1044x over previous
//
#include <hip/hip_runtime.h>
#include <math.h>

// SSIM loss, fp32 in, B=16 C=3 H=W=512, 11x11 Gaussian (sigma=1.5), zero pad.
// R16: guaranteed load pipeline via inline-asm buffer loads.
//   Post-mortems R12-R15: compiler sinks intrinsic loads to just before use
//   (VGPR pinned 32-48 across 4 rounds) -> ring never materializes -> each
//   wave exposes full HBM latency per chunk. R15 diagnostic: +75% requests
//   gave +40% BW (2.4->3.3 TB/s) => request-starved, not pattern-limited.
//   Fix: asm volatile buffer_load_dwordx4 (order immutable) into a 3-deep
//   register ring; consume only after explicit s_waitcnt vmcnt(N) +
//   sched_barrier(0) (hoist fence, rule: compiler hoists register-only ops
//   past inline-asm waitcnt otherwise). 12 loads (192B/lane) in flight.
//  - geometry = R13 (best, FETCH 101MB): TX=64, 4-wave blocks, TYS=128,
//    barrier-free main body; LDS = R15's proven 2-slot per-wave Ht ring
//    (20.5 KB/block). vconv (LDS-only) runs BEFORE the vmcnt wait each iter
//    so its MFMA/VALU work hides under in-flight loads.
// Math identical to R10-R15 (S=x+y, D=x-y planes, f16 pipeline, cv fixup).
// gfx950 v_mfma_f32_16x16x32_f16 layouts (verified R10-R15 pass):
//   A[i][k]: lane = i + 16*(k/8), elem = k%8
//   B[k][j]: lane = j + 16*(k/8), elem = k%8
//   D[r][c]: lane = c + 16*(r/4), reg  = r%4

#define IMG_W 512
#define IMG_H 512
#define PLANES 48
#define TX 64
#define TYS 128
#define RAD 5
#define NT 256
#define GDX (IMG_W / TX)            // 8
#define GDY (IMG_H / TYS)           // 4
#define NBLK (GDX * GDY * PLANES)   // 1536
#define NWAVES (NBLK * 4)           // 6144
#define NCH 9                       // hconv 16-row chunks (144 H rows)
#define CSTR 40                     // Ht col stride, f16 (2 slots*16 + 8 pad)
#define PSTR (16 * CSTR)            // Ht plane stride, f16 (640)
#define WSTR (4 * PSTR)             // Ht wave stride, f16 (2560)
#define NUMREC (IMG_W * IMG_H * 4)  // SRD num_records (bytes)
#define CHSTEP (16 * IMG_W * 4)     // voffset step per 16-row chunk (32768)
#define INVW  0.26601181f           // 1 / sum(exp(-(k-5)^2/4.5))
#define GC2   0.32059890f           // (1/4.5) * log2(e)

typedef _Float16 h2 __attribute__((ext_vector_type(2)));
typedef _Float16 h4 __attribute__((ext_vector_type(4)));
typedef _Float16 h8 __attribute__((ext_vector_type(8)));
typedef float f32x4 __attribute__((ext_vector_type(4)));
typedef int i32x4 __attribute__((ext_vector_type(4)));

__device__ __forceinline__ i32x4 make_srd(const float* p) {
    union { i32x4 v; struct { const float* p; unsigned rng; unsigned cfg; } s; } u;
    u.s.p = p; u.s.rng = NUMREC; u.s.cfg = 0x00020000u;
    return u.v;
}

// Counted wait on the asm-issued buffer loads + full scheduling fence so the
// compiler cannot hoist register-only consumers above the wait.
template<int N>
__device__ __forceinline__ void vwait() {
    asm volatile("s_waitcnt vmcnt(%0)" :: "n"(N) : "memory");
    __builtin_amdgcn_sched_barrier(0);
}

__device__ __forceinline__ float exp2_fast(float a) {
#if __has_builtin(__builtin_amdgcn_exp2f)
    return __builtin_amdgcn_exp2f(a);
#else
    return exp2f(a);
#endif
}

// Normalized f32 Gaussian weight w[idx], idx in [0,10], else 0.
__device__ __forceinline__ float wbandf(int idx) {
    const float fd = (float)(idx - 5);
    const float g = exp2_fast(-(fd * fd) * GC2) * INVW;
    return ((unsigned)idx <= 10u) ? g : 0.f;
}

__device__ __forceinline__ h2 pkrtz(float a, float b) {
    auto t = __builtin_amdgcn_cvt_pkrtz(a, b);
    h2 r;
    __builtin_memcpy(&r, &t, sizeof(r));
    return r;
}

__device__ __forceinline__ h4 pack4(f32x4 a) {
    const h2 lo = pkrtz(a[0], a[1]), hi = pkrtz(a[2], a[3]);
    h4 v;
    v[0] = lo.x; v[1] = lo.y; v[2] = hi.x; v[3] = hi.y;
    return v;
}

// One 16-row hconv chunk: regs -> s/d/s2/d2 MFMA -> transposed f16 Ht slot.
__device__ __forceinline__ void hconv_chunk(
    f32x4 xa, f32x4 xb, f32x4 ya, f32x4 yb, h8 whB,
    _Float16* wp)    // = Hw + fc*CSTR + 4*q + slot*16
{
    const f32x4 zz = {0.f, 0.f, 0.f, 0.f};
    const h2 xh0 = pkrtz(xa[0], xa[1]), xh1 = pkrtz(xa[2], xa[3]);
    const h2 xh2 = pkrtz(xb[0], xb[1]), xh3 = pkrtz(xb[2], xb[3]);
    const h2 yh0 = pkrtz(ya[0], ya[1]), yh1 = pkrtz(ya[2], ya[3]);
    const h2 yh2 = pkrtz(yb[0], yb[1]), yh3 = pkrtz(yb[2], yb[3]);
    const h2 s0 = xh0 + yh0, s1 = xh1 + yh1, s2 = xh2 + yh2, s3 = xh3 + yh3;
    const h2 d0 = xh0 - yh0, d1 = xh1 - yh1, d2 = xh2 - yh2, d3 = xh3 - yh3;
    h8 sA, dA;
    sA[0] = s0.x; sA[1] = s0.y; sA[2] = s1.x; sA[3] = s1.y;
    sA[4] = s2.x; sA[5] = s2.y; sA[6] = s3.x; sA[7] = s3.y;
    dA[0] = d0.x; dA[1] = d0.y; dA[2] = d1.x; dA[3] = d1.y;
    dA[4] = d2.x; dA[5] = d2.y; dA[6] = d3.x; dA[7] = d3.y;
    const h8 s2A = sA * sA;                       // v_pk_mul_f16
    const h8 d2A = dA * dA;
    const f32x4 hS  = __builtin_amdgcn_mfma_f32_16x16x32_f16(sA,  whB, zz, 0, 0, 0);
    const f32x4 hD  = __builtin_amdgcn_mfma_f32_16x16x32_f16(dA,  whB, zz, 0, 0, 0);
    const f32x4 hS2 = __builtin_amdgcn_mfma_f32_16x16x32_f16(s2A, whB, zz, 0, 0, 0);
    const f32x4 hD2 = __builtin_amdgcn_mfma_f32_16x16x32_f16(d2A, whB, zz, 0, 0, 0);
    *(h4*)(wp + 0 * PSTR) = pack4(hS);            // ds_write_b64
    *(h4*)(wp + 1 * PSTR) = pack4(hD);
    *(h4*)(wp + 2 * PSTR) = pack4(hS2);
    *(h4*)(wp + 3 * PSTR) = pack4(hD2);
}

// SSIM map for one completed out-chunk (4 rows of one col per lane).
__device__ __forceinline__ float mapsum(f32x4 aS, f32x4 aD, f32x4 aS2, f32x4 aD2,
                                        float cv)
{
    float local = 0.f;
    #pragma unroll
    for (int r = 0; r < 4; ++r) {
        const float mS = aS[r]  * cv, mD = aD[r]  * cv;
        const float eS = aS2[r] * cv, eD = aD2[r] * cv;
        const float ms2 = mS * mS, md2 = mD * mD;
        const float Pm = 0.5f * (ms2 - md2);   // = 2*mu_x*mu_y
        const float Qm = 0.5f * (ms2 + md2);   // = mu_x^2 + mu_y^2
        const float Pe = 0.5f * (eS - eD);     // = 2*E[xy]
        const float Qe = 0.5f * (eS + eD);     // = E[x^2 + y^2]
        const float c1 = 1e-4f, c2 = 9e-4f;
        const float num = (Pm + c1) * (Pe - Pm + c2);
        const float den = (Qm + c1) * (Qe - Qm + c2) + 1e-8f;
        local += num * __builtin_amdgcn_rcpf(den);
    }
    return local;
}

#define MFMA16(A, B, C) __builtin_amdgcn_mfma_f32_16x16x32_f16((A), (B), (C), 0, 0, 0)

// Issue one chunk's 4 loads (order fixed: asm volatile).
#define ISSUE(slot) do {                                                      \
    asm volatile("buffer_load_dwordx4 %0, %1, %2, 0 offen"                    \
                 : "=v"(LXA[slot]) : "v"(voff), "s"(srdx));                   \
    asm volatile("buffer_load_dwordx4 %0, %1, %2, 0 offen offset:16"          \
                 : "=v"(LXB[slot]) : "v"(voff), "s"(srdx));                   \
    asm volatile("buffer_load_dwordx4 %0, %1, %2, 0 offen"                    \
                 : "=v"(LYA[slot]) : "v"(voff), "s"(srdy));                   \
    asm volatile("buffer_load_dwordx4 %0, %1, %2, 0 offen offset:16"          \
                 : "=v"(LYB[slot]) : "v"(voff), "s"(srdy));                   \
    voff += CHSTEP;                                                           \
} while (0)

// vconv for out-chunk m (at iteration c = m+2): LDS-only, no vmem dep.
#define VCONV(C) do {                                                         \
    const _Float16* rp = rbase + ((((C) + qh) & 1) << 4);                     \
    const h8 B0 = *(const h8*)(rp + 0 * PSTR);   /* ds_read_b128 x4 */        \
    const h8 B1 = *(const h8*)(rp + 1 * PSTR);                                \
    const h8 B2 = *(const h8*)(rp + 2 * PSTR);                                \
    const h8 B3 = *(const h8*)(rp + 3 * PSTR);                                \
    const f32x4 aS  = MFMA16(wvA, B0, zz);                                    \
    const f32x4 aD  = MFMA16(wvA, B1, zz);                                    \
    const f32x4 aS2 = MFMA16(wvA, B2, zz);                                    \
    const f32x4 aD2 = MFMA16(wvA, B3, zz);                                    \
    local += mapsum(aS, aD, aS2, aD2, cv);                                    \
} while (0)

__global__ __launch_bounds__(NT, 4) void ssim_tile_kernel(
    const float* __restrict__ x, const float* __restrict__ y,
    float* __restrict__ partials)
{
    __shared__ __align__(16) _Float16 Ht[4 * WSTR];   // 20480 B

    const int tid = threadIdx.x;
    const int l = tid & 63, wid = tid >> 6;
    const int q = l >> 4, fc = l & 15;
    const int ql = q & 1, qh = q >> 1;

    const int plane = blockIdx.z;
    const i32x4 srdx = make_srd(x + (size_t)plane * IMG_H * IMG_W);
    const i32x4 srdy = make_srd(y + (size_t)plane * IMG_H * IMG_W);
    const int C0 = blockIdx.x * TX;
    const int R0 = blockIdx.y * TYS;
    const int c0 = 16 * wid;                    // this wave's out-col base
    const int gcol = C0 + c0 - 8 + 8 * q;       // A-frag global col start
    // Row OOB -> voffset outside [0,NUMREC) -> HW returns 0 (zero-pad).
    // Col OOB lanes (gcol=-8 or 512): permanently-OOB voffset.
    int voff = ((unsigned)gcol < (unsigned)IMG_W)
             ? (((R0 - RAD + fc) << 11) + (gcol << 2)) : 0x60000000;

    // ---- Prologue: issue chunks 0,1,2 into ring slots 0,1,2 ----
    f32x4 LXA[3], LXB[3], LYA[3], LYB[3];
    ISSUE(0); ISSUE(1); ISSUE(2);

    // ---- Weight setup (executes under the 12 in-flight loads) ----
    float s2w = 0.f;
    #pragma unroll
    for (int k = 0; k <= 10; ++k) s2w += (float)(_Float16)wbandf(k);
    const float cv = 1.f / (s2w * s2w);

    h8 whB, wvA;                 // hconv B-frag w[t-u-3], vconv A-frag w[t-u]
    #pragma unroll
    for (int e = 0; e < 8; ++e) {
        whB[e] = (_Float16)wbandf(8 * q + e - fc - 3);
        wvA[e] = (_Float16)wbandf(8 * q + e - fc);
    }

    _Float16* const Hw = Ht + wid * WSTR;                    // wave's region
    _Float16* const hwr = Hw + fc * CSTR + 4 * q;            // write base (+slot*16)
    const _Float16* const rbase = Hw + fc * CSTR + 8 * ql;   // read base (+slot*16)

    const f32x4 zz = {0.f, 0.f, 0.f, 0.f};
    float local = 0.f;

    // ---- Main loop: vconv m=c-2 (LDS-only, hides load latency) |
    //      wait chunk c | hconv c | issue c+3 ----
    #pragma unroll
    for (int c = 0; c < NCH; ++c) {
        if (c >= 2) VCONV(c);            // reads LDS chunks c-2 (slot c&1), c-1
        if (c <= 6) vwait<8>();          // retire chunk c (12 outstanding)
        else if (c == 7) vwait<4>();     // chunks 7,8 outstanding
        else vwait<0>();
        // hconv chunk c -> LDS slot c&1 (overwrites chunk c-2 AFTER the
        // VCONV reads above; same-wave DS ops execute in order)
        hconv_chunk(LXA[c % 3], LXB[c % 3], LYA[c % 3], LYB[c % 3],
                    whB, hwr + ((c & 1) << 4));
        if (c + 3 < NCH) ISSUE(c % 3);   // refill freed ring slot w/ chunk c+3
    }

    // ---- Epilogue: out chunk m=7 (reads LDS chunks 7,8) ----
    VCONV(9);

    // ---- Wave reduction -> one partial per wave (no barrier) ----
    #pragma unroll
    for (int off = 32; off > 0; off >>= 1)
        local += __shfl_down(local, off, 64);
    const int gid = (blockIdx.x + GDX * (blockIdx.y + GDY * blockIdx.z)) * 4 + wid;
    if (l == 0) partials[gid] = local;
}

__global__ __launch_bounds__(256) void ssim_finalize_kernel(
    const float* __restrict__ partials, float* __restrict__ out)
{
    const int tid = threadIdx.x;
    double s = 0.0;
    #pragma unroll 4
    for (int i = tid; i < NWAVES; i += 256) s += (double)partials[i];
    #pragma unroll
    for (int off = 32; off > 0; off >>= 1)
        s += __shfl_down(s, off, 64);
    __shared__ double ws_[256 / 64];
    const int lane = tid & 63, wv = tid >> 6;
    if (lane == 0) ws_[wv] = s;
    __syncthreads();
    if (tid == 0) {
        const double t = ws_[0] + ws_[1] + ws_[2] + ws_[3];
        const double n = (double)PLANES * IMG_H * IMG_W;
        out[0] = (float)(1.0 - t / n);
    }
}

extern "C" void kernel_launch(void* const* d_in, const int* in_sizes, int n_in,
                              void* d_out, int out_size, void* d_ws, size_t ws_size,
                              hipStream_t stream)
{
    const float* x = (const float*)d_in[0];
    const float* y = (const float*)d_in[1];
    float* out = (float*)d_out;
    float* partials = (float*)d_ws;   // NWAVES floats, fully overwritten each call

    dim3 grid(GDX, GDY, PLANES);
    ssim_tile_kernel<<<grid, NT, 0, stream>>>(x, y, partials);
    ssim_finalize_kernel<<<1, 256, 0, stream>>>(partials, out);
}